// Round 5
// baseline (1688.257 us; speedup 1.0000x reference)
//
#include <hip/hip_runtime.h>

typedef __attribute__((ext_vector_type(8))) short bf16x8;   // MFMA A/B frag
typedef __attribute__((ext_vector_type(4))) float f32x4;    // MFMA C/D frag
typedef __attribute__((ext_vector_type(4))) short s16x4;    // 4 bf16 (8 B)

__device__ __forceinline__ unsigned cvt_pk(float lo, float hi) {
  unsigned r;
  asm("v_cvt_pk_bf16_f32 %0, %1, %2" : "=v"(r) : "v"(lo), "v"(hi));
  return r;
}
__device__ __forceinline__ float bf2f(short s) {
  return __uint_as_float(((unsigned)(unsigned short)s) << 16);
}
__device__ __forceinline__ float sigm(float z) {
  return __builtin_amdgcn_rcpf(1.f + __builtin_amdgcn_exp2f(-1.44269504089f * z));
}
__device__ __forceinline__ float tanh_(float z) {
  return 1.f - 2.f * __builtin_amdgcn_rcpf(1.f + __builtin_amdgcn_exp2f(2.88539008178f * z));
}

// ---------- geometry ----------
// ws per component: 4 matrices as A-operand fragments (W^T strips), bf16.
//   mat m in {W1a(out),W1b(x),W2,W3}: frag (w,kc,lane) 16 B at ((w*4+kc)*64+l)*16
#define WS_MAT 32768
#define WS_COMP 131072
#define NODE_BLOCKS 1563
#define EDGE_BLOCKS 3125
#define GLOB_BLOCKS 16
#define NBLOCKS (NODE_BLOCKS + EDGE_BLOCKS + GLOB_BLOCKS)   // 4704

// swizzled byte offset within a [32 rows][256 B] LDS tile
#define SWZ(row, byte) ((row) * 256 + ((byte) ^ (((row) & 7) << 4)))

__global__ __launch_bounds__(256) void prep_weights(
    const float* __restrict__ W1, const float* __restrict__ W2,
    const float* __restrict__ W3, unsigned char* __restrict__ wsc) {
  const int m = blockIdx.x;   // 0=W1a 1=W1b 2=W2 3=W3
  const float* src; int rowoff = 0;
  if (m == 0)      { src = W1; }
  else if (m == 1) { src = W1; rowoff = 128; }
  else if (m == 2) { src = W2; }
  else             { src = W3; }
  short* dst = (short*)(wsc + (size_t)m * WS_MAT);
  for (int fi = threadIdx.x; fi < 2048; fi += 256) {
    int w = fi >> 8, kc = (fi >> 6) & 3, lane = fi & 63;
    int cc = lane & 15, gg = lane >> 4;
    int wcol = 16 * w + cc;
    int kb = 32 * kc + 8 * gg + rowoff;
    union { bf16x8 h; unsigned u[4]; } v;
#pragma unroll
    for (int j = 0; j < 4; ++j)
      v.u[j] = cvt_pk(src[(size_t)(kb + 2 * j) * 128 + wcol],
                      src[(size_t)(kb + 2 * j + 1) * 128 + wcol]);
    *(bf16x8*)(dst + (size_t)fi * 8) = v.h;
  }
}

// x-only precompute for one 16-row tile (produces u, g3, aAx for the NEXT step)
__device__ __forceinline__ void pre_tile(
    const char* xb, int row, int g, int w,
    const bf16x8* w1b, const bf16x8* w2, const bf16x8* w3,
    f32x4 b1v, f32x4 b2v, f32x4 b3v,
    f32x4& u, f32x4& g3, f32x4& aAx) {
  bf16x8 xf[4];
#pragma unroll
  for (int kc = 0; kc < 4; ++kc)
    xf[kc] = *(const bf16x8*)(xb + SWZ(row, 64 * kc + 16 * g));
  s16x4 xe4 = *(const s16x4*)(xb + SWZ(row, 32 * w + 8 * g));
  f32x4 aB = b2v, aC = b3v, aX = b1v;
#pragma unroll
  for (int kc = 0; kc < 4; ++kc) {
    aX = __builtin_amdgcn_mfma_f32_16x16x32_bf16(w1b[kc], xf[kc], aX, 0, 0, 0);
    aB = __builtin_amdgcn_mfma_f32_16x16x32_bf16(w2[kc],  xf[kc], aB, 0, 0, 0);
    aC = __builtin_amdgcn_mfma_f32_16x16x32_bf16(w3[kc],  xf[kc], aC, 0, 0, 0);
  }
#pragma unroll
  for (int ri = 0; ri < 4; ++ri) {
    u[ri]  = sigm(aB[ri]) * tanh_(bf2f(xe4[ri]));
    g3[ri] = sigm(aC[ri]);
  }
  aAx = aX;
}

// serial (recurrent) part for one 16-row tile; writes out(t) to obw unless last step
__device__ __forceinline__ void ser_tile(
    const char* ofsrc, char* obw, bool wr, int row, int g, int w,
    const bf16x8* w1a, f32x4 aAx, f32x4 u, f32x4 g3,
    f32x4& st) {
  bf16x8 of[4];
#pragma unroll
  for (int kc = 0; kc < 4; ++kc)
    of[kc] = *(const bf16x8*)(ofsrc + SWZ(row, 64 * kc + 16 * g));
  f32x4 aA = aAx;   // = x@W1b + b1 (precomputed)
#pragma unroll
  for (int kc = 0; kc < 4; ++kc)
    aA = __builtin_amdgcn_mfma_f32_16x16x32_bf16(w1a[kc], of[kc], aA, 0, 0, 0);
  f32x4 ov;
#pragma unroll
  for (int ri = 0; ri < 4; ++ri) {
    float fgt = sigm(aA[ri]);
    st[ri] = st[ri] * fgt + u[ri];
    ov[ri] = tanh_(st[ri]) * g3[ri];
  }
  if (wr) {
    union { s16x4 v; unsigned uu[2]; } ob;
    ob.uu[0] = cvt_pk(ov[0], ov[1]);
    ob.uu[1] = cvt_pk(ov[2], ov[3]);
    *(s16x4*)(obw + SWZ(row, 32 * w + 8 * g)) = ob.v;
  }
}

__global__ __launch_bounds__(512, 6) void glstm(
    const float* __restrict__ xs, const float* __restrict__ es,
    const float* __restrict__ gs, const unsigned char* __restrict__ ws,
    const float* __restrict__ b1n, const float* __restrict__ b2n, const float* __restrict__ b3n,
    const float* __restrict__ b1e, const float* __restrict__ b2e, const float* __restrict__ b3e,
    const float* __restrict__ b1g, const float* __restrict__ b2g, const float* __restrict__ b3g,
    float* __restrict__ dout) {
  // LDS: 3 x-buffers (8 KB) + 2 out-buffers (8 KB) = 40 KB -> 3 blocks/CU
  __shared__ __align__(16) unsigned char smem[40960];

  const int bid = blockIdx.x, tid = threadIdx.x;
  const float* X; const float *B1, *B2, *B3; float *S, *O; int M, unit, comp;
  if (bid < NODE_BLOCKS) {
    X = xs; M = 50000;  S = dout;              O = dout + 19265536L;
    unit = bid; comp = 0; B1 = b1n; B2 = b2n; B3 = b3n;
  } else if (bid < NODE_BLOCKS + EDGE_BLOCKS) {
    X = es; M = 100000; S = dout + 6400000L;   O = dout + 25665536L;
    unit = bid - NODE_BLOCKS; comp = 1; B1 = b1e; B2 = b2e; B3 = b3e;
  } else {
    X = gs; M = 512;    S = dout + 19200000L;  O = dout + 38465536L;
    unit = bid - (NODE_BLOCKS + EDGE_BLOCKS); comp = 2; B1 = b1g; B2 = b2g; B3 = b3g;
  }

  const int w = tid >> 6, l = tid & 63, c = l & 15, g = l >> 4;
  const int Ra = unit * 32;
  const bool v1 = (Ra + 16) < M;          // tile1 validity (M % 16 == 0)
  const int row0 = c, row1 = 16 + c;

  // weights -> registers (once)
  bf16x8 wA[4][4];
  {
    const short* wsrc = (const short*)(ws + (size_t)comp * WS_COMP);
#pragma unroll
    for (int m = 0; m < 4; ++m)
#pragma unroll
      for (int kc = 0; kc < 4; ++kc)
        wA[m][kc] = *(const bf16x8*)(wsrc + (size_t)m * 16384 + ((w * 4 + kc) * 64 + l) * 8);
  }
  const f32x4 b1v = *(const f32x4*)(B1 + 16 * w + 4 * g);
  const f32x4 b2v = *(const f32x4*)(B2 + 16 * w + 4 * g);
  const f32x4 b3v = *(const f32x4*)(B3 + 16 * w + 4 * g);

  char* xb0 = (char*)smem;
  char* xb1 = (char*)smem + 8192;
  char* xb2 = (char*)smem + 16384;
  char* ob0 = (char*)smem + 24576;
  char* ob1 = (char*)smem + 32768;

  const int srow = tid >> 4;
  const int sbyte = (tid & 15) * 16;      // bf16 byte col
  const int scol = (tid & 15) * 8;        // f32 col
  const bool sv = (Ra + srow) < M;

  // ---- prologue: stage x(0)->xb0, x(1)->xb1
  if (sv) {
    const float* p0 = X + (size_t)(Ra + srow) * 128 + scol;
    const float* p1 = p0 + (size_t)M * 128;
    f32x4 a0 = *(const f32x4*)p0, a1 = *(const f32x4*)(p0 + 4);
    f32x4 a2 = *(const f32x4*)p1, a3 = *(const f32x4*)(p1 + 4);
    union { bf16x8 h; unsigned u[4]; } o;
    o.u[0] = cvt_pk(a0[0], a0[1]); o.u[1] = cvt_pk(a0[2], a0[3]);
    o.u[2] = cvt_pk(a1[0], a1[1]); o.u[3] = cvt_pk(a1[2], a1[3]);
    *(bf16x8*)(xb0 + SWZ(srow, sbyte)) = o.h;
    o.u[0] = cvt_pk(a2[0], a2[1]); o.u[1] = cvt_pk(a2[2], a2[3]);
    o.u[2] = cvt_pk(a3[0], a3[1]); o.u[3] = cvt_pk(a3[2], a3[3]);
    *(bf16x8*)(xb1 + SWZ(srow, sbyte)) = o.h;
  }
  __syncthreads();

  // state init = x[0] (bf16-rounded); precompute step-0 x-terms from xb0
  f32x4 st0, st1;
  {
    s16x4 e0 = *(const s16x4*)(xb0 + SWZ(row0, 32 * w + 8 * g));
    s16x4 e1 = *(const s16x4*)(xb0 + SWZ(row1, 32 * w + 8 * g));
#pragma unroll
    for (int ri = 0; ri < 4; ++ri) { st0[ri] = bf2f(e0[ri]); st1[ri] = bf2f(e1[ri]); }
  }
  f32x4 u0, u1, g30, g31, aAx0, aAx1;
  pre_tile(xb0, row0, g, w, wA[1], wA[2], wA[3], b1v, b2v, b3v, u0, g30, aAx0);
  pre_tile(xb0, row1, g, w, wA[1], wA[2], wA[3], b1v, b2v, b3v, u1, g31, aAx1);

  // rotating buffers: xr holds x(t+1), xw = target for x(t+2), xsp spare (x(0) at t=0)
  char* xr = xb1; char* xw = xb2; char* xsp = xb0;
  char* orf = ob0; char* owf = ob1;

#pragma unroll 1
  for (int t = 0; t < 8; ++t) {
    // prefetch x(t+2) (issued early; written to LDS at step end)
    f32x4 pa, pb;
    const bool pf = (t < 6) && sv;
    if (pf) {
      const float* p = X + ((size_t)(t + 2) * M + Ra + srow) * 128 + scol;
      pa = *(const f32x4*)p; pb = *(const f32x4*)(p + 4);
    }

    // serial recurrent part (of = out(t-1); at t=0 out(-1)=x(0) in xsp)
    const char* ofs = (t == 0) ? (const char*)xsp : (const char*)orf;
    const bool wr = (t < 7);
    ser_tile(ofs, owf, wr, row0, g, w, wA[0], aAx0, u0, g30, st0);
    ser_tile(ofs, owf, wr, row1, g, w, wA[0], aAx1, u1, g31, st1);

    // precompute x-terms for step t+1 (independent of the serial chain)
    if (t < 7) {
      pre_tile(xr, row0, g, w, wA[1], wA[2], wA[3], b1v, b2v, b3v, u0, g30, aAx0);
      pre_tile(xr, row1, g, w, wA[1], wA[2], wA[3], b1v, b2v, b3v, u1, g31, aAx1);
    }

    // write staged x(t+2)
    if (pf) {
      union { bf16x8 h; unsigned u[4]; } o;
      o.u[0] = cvt_pk(pa[0], pa[1]); o.u[1] = cvt_pk(pa[2], pa[3]);
      o.u[2] = cvt_pk(pb[0], pb[1]); o.u[3] = cvt_pk(pb[2], pb[3]);
      *(bf16x8*)(xw + SWZ(srow, sbyte)) = o.h;
    }
    __syncthreads();

    // rotate buffers
    char* tx = xsp; xsp = xr; xr = xw; xw = tx;
    char* to = orf; orf = owf; owf = to;
  }

  // ---- epilogue: out = tanh(st)*g3 (g3 holds step-7 values), store f32
  {
    f32x4 ov0, ov1;
#pragma unroll
    for (int ri = 0; ri < 4; ++ri) {
      ov0[ri] = tanh_(st0[ri]) * g30[ri];
      ov1[ri] = tanh_(st1[ri]) * g31[ri];
    }
    size_t o0 = (size_t)(Ra + row0) * 128 + 16 * w + 4 * g;
    *(f32x4*)(S + o0) = st0;
    *(f32x4*)(O + o0) = ov0;
    if (v1) {
      size_t o1 = (size_t)(Ra + row1) * 128 + 16 * w + 4 * g;
      *(f32x4*)(S + o1) = st1;
      *(f32x4*)(O + o1) = ov1;
    }
  }
}

extern "C" void kernel_launch(void* const* d_in, const int* in_sizes, int n_in,
                              void* d_out, int out_size, void* d_ws, size_t ws_size,
                              hipStream_t stream) {
  (void)in_sizes; (void)n_in; (void)out_size; (void)ws_size;
  const float* xs = (const float*)d_in[0];
  const float* es = (const float*)d_in[1];
  const float* gs = (const float*)d_in[2];
  unsigned char* ws = (unsigned char*)d_ws;

  for (int comp = 0; comp < 3; ++comp) {
    const float* W1 = (const float*)d_in[3 + comp * 6 + 0];
    const float* W2 = (const float*)d_in[3 + comp * 6 + 2];
    const float* W3 = (const float*)d_in[3 + comp * 6 + 4];
    prep_weights<<<4, 256, 0, stream>>>(W1, W2, W3, ws + (size_t)comp * WS_COMP);
  }
  glstm<<<NBLOCKS, 512, 0, stream>>>(
      xs, es, gs, ws,
      (const float*)d_in[4],  (const float*)d_in[6],  (const float*)d_in[8],
      (const float*)d_in[10], (const float*)d_in[12], (const float*)d_in[14],
      (const float*)d_in[16], (const float*)d_in[18], (const float*)d_in[20],
      (float*)d_out);
}

// Round 6
// 333.697 us; speedup vs baseline: 5.0592x; 5.0592x over previous
//
#include <hip/hip_runtime.h>

typedef __attribute__((ext_vector_type(8))) short bf16x8;   // MFMA A/B frag
typedef __attribute__((ext_vector_type(4))) float f32x4;    // MFMA C/D frag
typedef __attribute__((ext_vector_type(4))) short s16x4;    // 4 bf16 (8 B)

__device__ __forceinline__ unsigned cvt_pk(float lo, float hi) {
  unsigned r;
  asm("v_cvt_pk_bf16_f32 %0, %1, %2" : "=v"(r) : "v"(lo), "v"(hi));
  return r;
}
__device__ __forceinline__ float bf2f(short s) {
  return __uint_as_float(((unsigned)(unsigned short)s) << 16);
}
__device__ __forceinline__ float sigm(float z) {
  return __builtin_amdgcn_rcpf(1.f + __builtin_amdgcn_exp2f(-1.44269504089f * z));
}
__device__ __forceinline__ float tanh_(float z) {
  return 1.f - 2.f * __builtin_amdgcn_rcpf(1.f + __builtin_amdgcn_exp2f(2.88539008178f * z));
}

// ---------- geometry ----------
// ws per component: 4 matrices as A-operand fragments (W^T strips), bf16.
//   mat m in {W1a(out),W1b(x),W2,W3}: frag (w,kc,lane) 16 B at ((w*4+kc)*64+l)*16
#define WS_MAT 32768
#define WS_COMP 131072
#define NODE_BLOCKS 1563
#define EDGE_BLOCKS 3125
#define GLOB_BLOCKS 16
#define NBLOCKS (NODE_BLOCKS + EDGE_BLOCKS + GLOB_BLOCKS)   // 4704

// swizzled byte offset within a [32 rows][256 B] LDS tile
#define SWZ(row, byte) ((row) * 256 + ((byte) ^ (((row) & 7) << 4)))
#define BIAS_OFF 40960            // f32[384] biases in LDS

__global__ __launch_bounds__(256) void prep_weights(
    const float* __restrict__ W1, const float* __restrict__ W2,
    const float* __restrict__ W3, unsigned char* __restrict__ wsc) {
  const int m = blockIdx.x;   // 0=W1a 1=W1b 2=W2 3=W3
  const float* src; int rowoff = 0;
  if (m == 0)      { src = W1; }
  else if (m == 1) { src = W1; rowoff = 128; }
  else if (m == 2) { src = W2; }
  else             { src = W3; }
  short* dst = (short*)(wsc + (size_t)m * WS_MAT);
  for (int fi = threadIdx.x; fi < 2048; fi += 256) {
    int w = fi >> 8, kc = (fi >> 6) & 3, lane = fi & 63;
    int cc = lane & 15, gg = lane >> 4;
    int wcol = 16 * w + cc;
    int kb = 32 * kc + 8 * gg + rowoff;
    union { bf16x8 h; unsigned u[4]; } v;
#pragma unroll
    for (int j = 0; j < 4; ++j)
      v.u[j] = cvt_pk(src[(size_t)(kb + 2 * j) * 128 + wcol],
                      src[(size_t)(kb + 2 * j + 1) * 128 + wcol]);
    *(bf16x8*)(dst + (size_t)fi * 8) = v.h;
  }
}

// x-only precompute for one 16-row tile (produces u, g3, aAx for the NEXT step).
// biases come from LDS each call (keeps them out of persistent VGPRs).
__device__ __forceinline__ void pre_tile(
    const char* xb, const float* blds, int row, int g, int w,
    const bf16x8* w1b, const bf16x8* w2, const bf16x8* w3,
    f32x4& u, f32x4& g3, f32x4& aAx) {
  bf16x8 xf[4];
#pragma unroll
  for (int kc = 0; kc < 4; ++kc)
    xf[kc] = *(const bf16x8*)(xb + SWZ(row, 64 * kc + 16 * g));
  s16x4 xe4 = *(const s16x4*)(xb + SWZ(row, 32 * w + 8 * g));
  const int bo = 16 * w + 4 * g;
  f32x4 aX = *(const f32x4*)(blds + bo);
  f32x4 aB = *(const f32x4*)(blds + 128 + bo);
  f32x4 aC = *(const f32x4*)(blds + 256 + bo);
#pragma unroll
  for (int kc = 0; kc < 4; ++kc) {
    aX = __builtin_amdgcn_mfma_f32_16x16x32_bf16(w1b[kc], xf[kc], aX, 0, 0, 0);
    aB = __builtin_amdgcn_mfma_f32_16x16x32_bf16(w2[kc],  xf[kc], aB, 0, 0, 0);
    aC = __builtin_amdgcn_mfma_f32_16x16x32_bf16(w3[kc],  xf[kc], aC, 0, 0, 0);
  }
#pragma unroll
  for (int ri = 0; ri < 4; ++ri) {
    u[ri]  = sigm(aB[ri]) * tanh_(bf2f(xe4[ri]));
    g3[ri] = sigm(aC[ri]);
  }
  aAx = aX;
}

// serial (recurrent) part for one 16-row tile; writes out(t) to obw unless last step
__device__ __forceinline__ void ser_tile(
    const char* ofsrc, char* obw, bool wr, int row, int g, int w,
    const bf16x8* w1a, f32x4 aAx, f32x4 u, f32x4 g3,
    f32x4& st) {
  bf16x8 of[4];
#pragma unroll
  for (int kc = 0; kc < 4; ++kc)
    of[kc] = *(const bf16x8*)(ofsrc + SWZ(row, 64 * kc + 16 * g));
  f32x4 aA = aAx;   // = x@W1b + b1 (precomputed)
#pragma unroll
  for (int kc = 0; kc < 4; ++kc)
    aA = __builtin_amdgcn_mfma_f32_16x16x32_bf16(w1a[kc], of[kc], aA, 0, 0, 0);
  f32x4 ov;
#pragma unroll
  for (int ri = 0; ri < 4; ++ri) {
    float fgt = sigm(aA[ri]);
    st[ri] = st[ri] * fgt + u[ri];
    ov[ri] = tanh_(st[ri]) * g3[ri];
  }
  if (wr) {
    union { s16x4 v; unsigned uu[2]; } ob;
    ob.uu[0] = cvt_pk(ov[0], ov[1]);
    ob.uu[1] = cvt_pk(ov[2], ov[3]);
    *(s16x4*)(obw + SWZ(row, 32 * w + 8 * g)) = ob.v;
  }
}

__global__ __launch_bounds__(512, 2) void glstm(
    const float* __restrict__ xs, const float* __restrict__ es,
    const float* __restrict__ gs, const unsigned char* __restrict__ ws,
    const float* __restrict__ b1n, const float* __restrict__ b2n, const float* __restrict__ b3n,
    const float* __restrict__ b1e, const float* __restrict__ b2e, const float* __restrict__ b3e,
    const float* __restrict__ b1g, const float* __restrict__ b2g, const float* __restrict__ b3g,
    float* __restrict__ dout) {
  // LDS: 3 x-buffers + 2 out-buffers (40 KB) + biases (1.5 KB)
  __shared__ __align__(16) unsigned char smem[42496];

  const int bid = blockIdx.x, tid = threadIdx.x;
  const float* X; const float *B1, *B2, *B3; float *S, *O; int M, unit, comp;
  if (bid < NODE_BLOCKS) {
    X = xs; M = 50000;  S = dout;              O = dout + 19265536L;
    unit = bid; comp = 0; B1 = b1n; B2 = b2n; B3 = b3n;
  } else if (bid < NODE_BLOCKS + EDGE_BLOCKS) {
    X = es; M = 100000; S = dout + 6400000L;   O = dout + 25665536L;
    unit = bid - NODE_BLOCKS; comp = 1; B1 = b1e; B2 = b2e; B3 = b3e;
  } else {
    X = gs; M = 512;    S = dout + 19200000L;  O = dout + 38465536L;
    unit = bid - (NODE_BLOCKS + EDGE_BLOCKS); comp = 2; B1 = b1g; B2 = b2g; B3 = b3g;
  }

  const int w = tid >> 6, l = tid & 63, c = l & 15, g = l >> 4;
  const int Ra = unit * 32;
  const bool v1 = (Ra + 16) < M;          // tile1 validity (M % 16 == 0)
  const int row0 = c, row1 = 16 + c;

  // weights -> registers (once)
  bf16x8 wA[4][4];
  {
    const short* wsrc = (const short*)(ws + (size_t)comp * WS_COMP);
#pragma unroll
    for (int m = 0; m < 4; ++m)
#pragma unroll
      for (int kc = 0; kc < 4; ++kc)
        wA[m][kc] = *(const bf16x8*)(wsrc + (size_t)m * 16384 + ((w * 4 + kc) * 64 + l) * 8);
  }

  char* xb0 = (char*)smem;
  char* xb1 = (char*)smem + 8192;
  char* xb2 = (char*)smem + 16384;
  char* ob0 = (char*)smem + 24576;
  char* ob1 = (char*)smem + 32768;
  float* blds = (float*)(smem + BIAS_OFF);

  // stage biases -> LDS (stays out of persistent VGPRs)
  if (tid < 128) {
    blds[tid]       = B1[tid];
    blds[128 + tid] = B2[tid];
    blds[256 + tid] = B3[tid];
  }

  const int srow = tid >> 4;
  const int sbyte = (tid & 15) * 16;      // bf16 byte col
  const int scol = (tid & 15) * 8;        // f32 col
  const bool sv = (Ra + srow) < M;

  // ---- prologue: stage x(0)->xb0, x(1)->xb1
  if (sv) {
    const float* p0 = X + (size_t)(Ra + srow) * 128 + scol;
    const float* p1 = p0 + (size_t)M * 128;
    f32x4 a0 = *(const f32x4*)p0, a1 = *(const f32x4*)(p0 + 4);
    f32x4 a2 = *(const f32x4*)p1, a3 = *(const f32x4*)(p1 + 4);
    union { bf16x8 h; unsigned u[4]; } o;
    o.u[0] = cvt_pk(a0[0], a0[1]); o.u[1] = cvt_pk(a0[2], a0[3]);
    o.u[2] = cvt_pk(a1[0], a1[1]); o.u[3] = cvt_pk(a1[2], a1[3]);
    *(bf16x8*)(xb0 + SWZ(srow, sbyte)) = o.h;
    o.u[0] = cvt_pk(a2[0], a2[1]); o.u[1] = cvt_pk(a2[2], a2[3]);
    o.u[2] = cvt_pk(a3[0], a3[1]); o.u[3] = cvt_pk(a3[2], a3[3]);
    *(bf16x8*)(xb1 + SWZ(srow, sbyte)) = o.h;
  }
  __syncthreads();

  // state init = x[0] (bf16-rounded); precompute step-0 x-terms from xb0
  f32x4 st0, st1;
  {
    s16x4 e0 = *(const s16x4*)(xb0 + SWZ(row0, 32 * w + 8 * g));
    s16x4 e1 = *(const s16x4*)(xb0 + SWZ(row1, 32 * w + 8 * g));
#pragma unroll
    for (int ri = 0; ri < 4; ++ri) { st0[ri] = bf2f(e0[ri]); st1[ri] = bf2f(e1[ri]); }
  }
  f32x4 u0, u1, g30, g31, aAx0, aAx1;
  pre_tile(xb0, blds, row0, g, w, wA[1], wA[2], wA[3], u0, g30, aAx0);
  pre_tile(xb0, blds, row1, g, w, wA[1], wA[2], wA[3], u1, g31, aAx1);

  // rotating buffers: xr holds x(t+1), xw = target for x(t+2), xsp spare (x(0) at t=0)
  char* xr = xb1; char* xw = xb2; char* xsp = xb0;
  char* orf = ob0; char* owf = ob1;

#pragma unroll 1
  for (int t = 0; t < 8; ++t) {
    // prefetch x(t+2) (issued early; written to LDS at step end)
    f32x4 pa, pb;
    const bool pf = (t < 6) && sv;
    if (pf) {
      const float* p = X + ((size_t)(t + 2) * M + Ra + srow) * 128 + scol;
      pa = *(const f32x4*)p; pb = *(const f32x4*)(p + 4);
    }

    // serial recurrent part (of = out(t-1); at t=0 out(-1)=x(0) in xsp)
    const char* ofs = (t == 0) ? (const char*)xsp : (const char*)orf;
    const bool wr = (t < 7);
    ser_tile(ofs, owf, wr, row0, g, w, wA[0], aAx0, u0, g30, st0);
    ser_tile(ofs, owf, wr, row1, g, w, wA[0], aAx1, u1, g31, st1);

    // precompute x-terms for step t+1 (independent of the serial chain)
    if (t < 7) {
      pre_tile(xr, blds, row0, g, w, wA[1], wA[2], wA[3], u0, g30, aAx0);
      pre_tile(xr, blds, row1, g, w, wA[1], wA[2], wA[3], u1, g31, aAx1);
    }

    // write staged x(t+2)
    if (pf) {
      union { bf16x8 h; unsigned u[4]; } o;
      o.u[0] = cvt_pk(pa[0], pa[1]); o.u[1] = cvt_pk(pa[2], pa[3]);
      o.u[2] = cvt_pk(pb[0], pb[1]); o.u[3] = cvt_pk(pb[2], pb[3]);
      *(bf16x8*)(xw + SWZ(srow, sbyte)) = o.h;
    }
    __syncthreads();

    // rotate buffers
    char* tx = xsp; xsp = xr; xr = xw; xw = tx;
    char* to = orf; orf = owf; owf = to;
  }

  // ---- epilogue: out = tanh(st)*g3 (g3 holds step-7 values), store f32
  {
    f32x4 ov0, ov1;
#pragma unroll
    for (int ri = 0; ri < 4; ++ri) {
      ov0[ri] = tanh_(st0[ri]) * g30[ri];
      ov1[ri] = tanh_(st1[ri]) * g31[ri];
    }
    size_t o0 = (size_t)(Ra + row0) * 128 + 16 * w + 4 * g;
    *(f32x4*)(S + o0) = st0;
    *(f32x4*)(O + o0) = ov0;
    if (v1) {
      size_t o1 = (size_t)(Ra + row1) * 128 + 16 * w + 4 * g;
      *(f32x4*)(S + o1) = st1;
      *(f32x4*)(O + o1) = ov1;
    }
  }
}

extern "C" void kernel_launch(void* const* d_in, const int* in_sizes, int n_in,
                              void* d_out, int out_size, void* d_ws, size_t ws_size,
                              hipStream_t stream) {
  (void)in_sizes; (void)n_in; (void)out_size; (void)ws_size;
  const float* xs = (const float*)d_in[0];
  const float* es = (const float*)d_in[1];
  const float* gs = (const float*)d_in[2];
  unsigned char* ws = (unsigned char*)d_ws;

  for (int comp = 0; comp < 3; ++comp) {
    const float* W1 = (const float*)d_in[3 + comp * 6 + 0];
    const float* W2 = (const float*)d_in[3 + comp * 6 + 2];
    const float* W3 = (const float*)d_in[3 + comp * 6 + 4];
    prep_weights<<<4, 256, 0, stream>>>(W1, W2, W3, ws + (size_t)comp * WS_COMP);
  }
  glstm<<<NBLOCKS, 512, 0, stream>>>(
      xs, es, gs, ws,
      (const float*)d_in[4],  (const float*)d_in[6],  (const float*)d_in[8],
      (const float*)d_in[10], (const float*)d_in[12], (const float*)d_in[14],
      (const float*)d_in[16], (const float*)d_in[18], (const float*)d_in[20],
      (float*)d_out);
}